// Round 13
// baseline (183.534 us; speedup 1.0000x reference)
//
#include <hip/hip_runtime.h>
#include <hip/hip_bf16.h>

// Fused MHA, B=8, S=1024, H=8, DK=128, D=1024, fp32 in/out, bf16 MFMA compute.
// convert(weights only) -> QKV proj (128x128 3-buffer lead-2 counted-vmcnt GEMM,
// A = raw f32 DMA'd into LDS via global_load_lds, converted at the LDS->reg read;
// 1536 blocks = 6 exact rounds, XCD swizzle, V^T epilogue) -> flash attn
// (QBLK=128, swapped-QK in-lane softmax, cvt_pk, XCD swizzle, fused arrange)
// -> out proj (256x128 3-buffer gemmS, 256 blocks = 1 round, fp32 out).

typedef __attribute__((ext_vector_type(8))) __bf16 bf16x8;
typedef __attribute__((ext_vector_type(4))) float f32x4;

#define DEV static __device__ __forceinline__

DEV float exp2v(float x) { return __builtin_amdgcn_exp2f(x); }

DEV unsigned short f2bf(float f) {
  union { float f; unsigned int u; } c; c.f = f;
  unsigned int u = c.u + 0x7fffu + ((c.u >> 16) & 1u);
  return (unsigned short)(u >> 16);
}

DEV unsigned cvtpk(float a, float b) {
  unsigned r;
  asm("v_cvt_pk_bf16_f32 %0, %1, %2" : "=v"(r) : "v"(a), "v"(b));
  return r;
}

DEV void gload16(const void* g, void* l) {
  __builtin_amdgcn_global_load_lds((const __attribute__((address_space(1))) void*)g,
                                   (__attribute__((address_space(3))) void*)l, 16, 0, 0);
}

#define LGKM0 asm volatile("s_waitcnt lgkmcnt(0)" ::: "memory")
#define BAR   __builtin_amdgcn_s_barrier()
#define VMC6  asm volatile("s_waitcnt vmcnt(6)" ::: "memory")
#define VMC0  asm volatile("s_waitcnt vmcnt(0)" ::: "memory")

// ---------------- convert: weights fp32->bf16 only ----------------
DEV void cv4(const float* __restrict__ s, unsigned short* __restrict__ d, int i) {
  const float4 a = *(const float4*)(s + i);
  ushort4 o;
  o.x = f2bf(a.x); o.y = f2bf(a.y); o.z = f2bf(a.z); o.w = f2bf(a.w);
  *(ushort4*)(d + i) = o;
}

__global__ __launch_bounds__(256) void convert_w(
    const float* __restrict__ wq, const float* __restrict__ wk,
    const float* __restrict__ wv, const float* __restrict__ wo,
    unsigned short* __restrict__ wb)
{
  const int i = (blockIdx.x * 256 + threadIdx.x) * 4;   // 4096 blocks x 1024 elems
  const int which = i >> 20, off = i & 1048575;
  const float* s = which == 0 ? wq : which == 1 ? wk : which == 2 ? wv : wo;
  cv4(s, wb + (which << 20), off);
}

// ---------------- fused QKV GEMM: 128x128, 3-buffer lead-2, f32 A in LDS ----------------
// C[m,n] = sum_k A[m,k]*W[n,k] + bias[n], A raw f32, W bf16. K=1024 = 16 BK=64 tiles.
// 512 thr = 8 waves (4M x 2N), per-wave 32x64 (acc[2][4]).
// LDS 144 KiB: A f32 3buf x 128row x 256B @0; B bf16 3buf x 128row x 128B @98304.
// A swizzle: byte ^= (row&7)<<5 (32B granule, 256B rows); B swizzle: <<4 (128B rows).
// Per tile (1 phase): {rdA(f32+cvt_pk) + rdB | stage A,B(t+2) | BAR lgkm0 | 16 MFMA
// | VMC6 | BAR}. Ledger: 6 loads/tile (4 A + 2 B), lead 2 -> gate leaves t+2's 6.
// z: 0=Q (scaled bf16), 1=K (bf16), 2=V -> VT[b,h,dk,s] packed. 1536 blocks = 6 rounds.
__global__ __launch_bounds__(512, 1) void gemmF(
    const float* __restrict__ Aq, const float* __restrict__ Ak,
    const float* __restrict__ Av, const unsigned short* __restrict__ wb,
    const float* __restrict__ bq, const float* __restrict__ bk,
    const float* __restrict__ bv,
    unsigned short* __restrict__ Qp, unsigned short* __restrict__ Kp,
    unsigned short* __restrict__ VTp)
{
  __shared__ __align__(16) char LDS[147456];
  // 1536 blocks = 8 XCD x 192
  const int swz = (blockIdx.x & 7) * 192 + (blockIdx.x >> 3);
  const int z = swz >> 9;               // 512 blocks per GEMM
  const int rem = swz & 511;
  const int mt = rem >> 3, nt = rem & 7;
  const int m0 = mt * 128, n0 = nt * 128;
  const float* Af = z == 0 ? Aq : z == 1 ? Ak : Av;
  const unsigned short* Bg = wb + ((size_t)z << 20);
  const float* bias = z == 0 ? bq : z == 1 ? bk : bv;

  const int tid = threadIdx.x, lane = tid & 63, w = tid >> 6;
  const int wm = w >> 1, wn = w & 1;    // 4M x 2N wave grid, per-wave 32x64
  const int g = lane >> 4, ln = lane & 15;

  const f32x4 fzero = {0.f, 0.f, 0.f, 0.f};
  f32x4 acc[2][4];
#pragma unroll
  for (int i = 0; i < 2; i++)
#pragma unroll
    for (int j = 0; j < 4; j++) acc[i][j] = fzero;

  bf16x8 bfr[4][2], afr[2][2];

  // A stage: raw f32, 32KB/buf, 4 gload16/thread; rows 256B; swizzle <<5
  auto SA = [&](int bf, int k0) {
#pragma unroll
    for (int i = 0; i < 4; ++i) {
      const int o = i * 8192 + tid * 16;
      const int row = o >> 8, cb = o & 255;
      gload16(Af + (size_t)(m0 + row) * 1024 + k0 + ((cb ^ ((row & 7) << 5)) >> 2),
              LDS + bf * 32768 + o);
    }
  };
  // B stage: bf16, 16KB/buf, 2 gload16/thread; rows 128B; swizzle <<4
  auto SB = [&](int bf, int k0) {
#pragma unroll
    for (int i = 0; i < 2; ++i) {
      const int o = i * 8192 + tid * 16;
      const int row = o >> 7, cb = o & 127;
      gload16(Bg + (size_t)(n0 + row) * 1024 + k0 + ((cb ^ ((row & 7) << 4)) >> 1),
              LDS + 98304 + bf * 16384 + o);
    }
  };
  // A frag read: two b128 of f32 + 4 cvt_pk -> bf16x8 (k0..k7 in order)
  auto rdA = [&](int bf) {
#pragma unroll
    for (int p = 0; p < 2; ++p) {
      const int row = wm * 32 + p * 16 + ln;
      const int sw = (row & 7) << 5;
#pragma unroll
      for (int kc = 0; kc < 2; ++kc) {
        const int c = (kc * 128 + g * 32) ^ sw;    // 32B-aligned; +16 same granule
        const char* base = LDS + bf * 32768 + row * 256;
        const f32x4 lo = *(const f32x4*)(base + c);
        const f32x4 hi = *(const f32x4*)(base + c + 16);
        union { unsigned u[4]; bf16x8 v; } cv;
        cv.u[0] = cvtpk(lo[0], lo[1]); cv.u[1] = cvtpk(lo[2], lo[3]);
        cv.u[2] = cvtpk(hi[0], hi[1]); cv.u[3] = cvtpk(hi[2], hi[3]);
        afr[p][kc] = cv.v;
      }
    }
  };
  auto rdB = [&](int bf) {
#pragma unroll
    for (int nf = 0; nf < 4; ++nf) {
      const int row = wn * 64 + nf * 16 + ln;
      const int sw = (row & 7) << 4;
#pragma unroll
      for (int kc = 0; kc < 2; ++kc)
        bfr[nf][kc] = *(const bf16x8*)(LDS + 98304 + bf * 16384 + row * 128 +
                                       ((kc * 64 + g * 16) ^ sw));
    }
  };
  auto mm = [&]() {
    __builtin_amdgcn_s_setprio(1);
#pragma unroll
    for (int p = 0; p < 2; ++p)
#pragma unroll
      for (int nf = 0; nf < 4; ++nf)
#pragma unroll
        for (int kc = 0; kc < 2; ++kc)
          acc[p][nf] = __builtin_amdgcn_mfma_f32_16x16x32_bf16(afr[p][kc], bfr[nf][kc],
                                                               acc[p][nf], 0, 0, 0);
    __builtin_amdgcn_s_setprio(0);
  };

  // prologue: tiles 0,1 staged (12 loads); gate leaves tile1's 6 in flight
  SA(0, 0); SB(0, 0);
  SA(1, 64); SB(1, 64);
  VMC6; BAR;

  int br = 0, bw = 2;
  for (int t = 0; t < 16; ++t) {
    const int kL = (t + 2) << 6;
    rdA(br); rdB(br);
    if (t < 14) { SA(bw, kL); SB(bw, kL); }
    BAR; LGKM0;
    mm();
    if (t < 14) { VMC6; } else if (t == 14) { VMC0; }
    BAR;
    br = br == 2 ? 0 : br + 1;
    bw = bw == 2 ? 0 : bw + 1;
  }

  // epilogue
  const float QS = 0.12751743f;   // 1/sqrt(128)*log2(e)
#pragma unroll
  for (int mf = 0; mf < 2; ++mf)
#pragma unroll
    for (int nf = 0; nf < 4; ++nf) {
      const int m = m0 + wm * 32 + mf * 16 + g * 4;
      const int n = n0 + wn * 64 + nf * 16 + ln;
      const float bn = bias[n];
      if (z == 0) {
#pragma unroll
        for (int r = 0; r < 4; ++r)
          Qp[(size_t)(m + r) * 1024 + n] = f2bf((acc[mf][nf][r] + bn) * QS);
      } else if (z == 1) {
#pragma unroll
        for (int r = 0; r < 4; ++r)
          Kp[(size_t)(m + r) * 1024 + n] = f2bf(acc[mf][nf][r] + bn);
      } else {
        const int b = m >> 10, s0 = m & 1023;   // n = h*128+dk; 4 rows same b
        uint2 pk;
        pk.x = cvtpk(acc[mf][nf][0] + bn, acc[mf][nf][1] + bn);
        pk.y = cvtpk(acc[mf][nf][2] + bn, acc[mf][nf][3] + bn);
        *(uint2*)(VTp + (((size_t)(b * 1024 + n)) << 10) + s0) = pk;
      }
    }
}

// ---------------- out projection: 256x128 3-buffer lead-2 (r10/r12 gemmS, bf16 A) ----------------
__global__ __launch_bounds__(512, 1) void gemm_out(
    const unsigned short* __restrict__ Abf, const unsigned short* __restrict__ Bg,
    const float* __restrict__ bias, float* __restrict__ fout)
{
  __shared__ __align__(16) char LDS[147456];
  const int swz = (blockIdx.x & 7) * 32 + (blockIdx.x >> 3);   // 256 = 8 x 32
  const int mt = swz >> 3, nt = swz & 7;
  const int m0 = mt * 256, n0 = nt * 128;

  const int tid = threadIdx.x, lane = tid & 63, w = tid >> 6;
  const int wm = w >> 1, wn = w & 1;
  const int g = lane >> 4, ln = lane & 15;

  const f32x4 fzero = {0.f, 0.f, 0.f, 0.f};
  f32x4 acc[4][4];
#pragma unroll
  for (int i = 0; i < 4; i++)
#pragma unroll
    for (int j = 0; j < 4; j++) acc[i][j] = fzero;

  bf16x8 bfr[4][2], afr[4][2];

  auto SA = [&](int bf, int hf, int k0) {
    const unsigned short* src = Abf + (size_t)(m0 + hf * 128) * 1024 + k0;
    char* base = LDS + bf * 32768 + hf * 16384 + w * 2048;
#pragma unroll
    for (int r2 = 0; r2 < 2; ++r2) {
      const int o = w * 2048 + r2 * 1024 + lane * 16;
      const int rwi = o >> 7, cb = o & 127;
      gload16(src + (size_t)rwi * 1024 + ((cb ^ ((rwi & 7) << 4)) >> 1), base + r2 * 1024);
    }
  };
  auto SB = [&](int bf, int k0) {
    const unsigned short* src = Bg + (size_t)n0 * 1024 + k0;
    char* base = LDS + 98304 + bf * 16384 + w * 2048;
#pragma unroll
    for (int r2 = 0; r2 < 2; ++r2) {
      const int o = w * 2048 + r2 * 1024 + lane * 16;
      const int rwi = o >> 7, cb = o & 127;
      gload16(src + (size_t)rwi * 1024 + ((cb ^ ((rwi & 7) << 4)) >> 1), base + r2 * 1024);
    }
  };
  auto rdA = [&](int bf, int q) {
#pragma unroll
    for (int p = 0; p < 2; ++p) {
      const int row = wm * 64 + (2 * q + p) * 16 + ln;
      const int sw = (row & 7) << 4;
#pragma unroll
      for (int kc = 0; kc < 2; ++kc)
        afr[2 * q + p][kc] = *(const bf16x8*)(LDS + bf * 32768 + row * 128 + ((kc * 64 + g * 16) ^ sw));
    }
  };
  auto rdB = [&](int bf) {
#pragma unroll
    for (int nf = 0; nf < 4; ++nf) {
      const int row = wn * 64 + nf * 16 + ln;
      const int sw = (row & 7) << 4;
#pragma unroll
      for (int kc = 0; kc < 2; ++kc)
        bfr[nf][kc] = *(const bf16x8*)(LDS + 98304 + bf * 16384 + row * 128 + ((kc * 64 + g * 16) ^ sw));
    }
  };
  auto mm = [&](int q) {
    __builtin_amdgcn_s_setprio(1);
#pragma unroll
    for (int p = 0; p < 2; ++p)
#pragma unroll
      for (int nf = 0; nf < 4; ++nf)
#pragma unroll
        for (int kc = 0; kc < 2; ++kc)
          acc[2 * q + p][nf] =
              __builtin_amdgcn_mfma_f32_16x16x32_bf16(afr[2 * q + p][kc], bfr[nf][kc],
                                                      acc[2 * q + p][nf], 0, 0, 0);
    __builtin_amdgcn_s_setprio(0);
  };

  SA(0, 0, 0); SA(0, 1, 0); SB(0, 0);
  SA(1, 0, 64); SA(1, 1, 64); SB(1, 64);
  VMC6; BAR;

  int br = 0, bw = 2;
  for (int t = 0; t < 16; ++t) {
    const int kL = (t + 2) << 6;
    rdB(br); rdA(br, 0); rdA(br, 1);
    if (t < 14) { SA(bw, 0, kL); SA(bw, 1, kL); SB(bw, kL); }
    BAR; LGKM0;
    mm(0); mm(1);
    if (t < 14) { VMC6; } else if (t == 14) { VMC0; }
    BAR;
    br = br == 2 ? 0 : br + 1;
    bw = bw == 2 ? 0 : bw + 1;
  }

#pragma unroll
  for (int mf = 0; mf < 4; ++mf)
#pragma unroll
    for (int nf = 0; nf < 4; ++nf) {
      const int m = m0 + wm * 64 + mf * 16 + g * 4;
      const int n = n0 + wn * 64 + nf * 16 + ln;
      const float bn = bias[n];
#pragma unroll
      for (int r = 0; r < 4; ++r)
        fout[(size_t)(m + r) * 1024 + n] = acc[mf][nf][r] + bn;
    }
}

// ---------------- flash attention + fused attn_arrange (+zero pad) ----------------
// Grid 512 = 8 qb x 64 (b,h); XCD-coherent. 512 thr = 8 waves x 16 q-rows (QBLK 128).
__global__ __launch_bounds__(512) void attn_kernel(
    const unsigned short* __restrict__ Qp, const unsigned short* __restrict__ Kp,
    const unsigned short* __restrict__ VT, const int* __restrict__ cfg,
    unsigned short* __restrict__ ret)
{
  __shared__ __align__(16) unsigned short Ks[2][64 * 128];
  __shared__ __align__(16) unsigned short Vs[2][128 * 64];
  __shared__ __align__(16) unsigned short Ps[8 * 16 * 64];
  const int bx = blockIdx.x;
  const int qb = bx >> 6, bh = bx & 63, b = bh >> 3, h = bh & 7;
  const int tid = threadIdx.x, lane = tid & 63, w = tid >> 6;
  const int g = lane >> 4, ln = lane & 15;
  const int q0 = qb * 128;
  const f32x4 fzero = {0.f, 0.f, 0.f, 0.f};

  bf16x8 qf[4];
  {
    const unsigned short* qrow = Qp + ((size_t)(b * 1024 + q0 + w * 16 + ln)) * 1024 + h * 128;
#pragma unroll
    for (int kc = 0; kc < 4; kc++) qf[kc] = *(const bf16x8*)(qrow + kc * 32 + g * 8);
  }
  float m_run = -1e30f, l_run = 0.f;
  f32x4 o_acc[8];
#pragma unroll
  for (int i = 0; i < 8; i++) o_acc[i] = fzero;

  auto stage = [&](int buf, int kv0) {
#pragma unroll
    for (int i = 0; i < 2; ++i) {
      const int o = i * 8192 + tid * 16;
      {
        const int r = o >> 8, cb = o & 255;
        const int cs = cb ^ ((r & 7) << 4);
        gload16(Kp + ((size_t)(b * 1024 + kv0 + r)) * 1024 + h * 128 + (cs >> 1),
                (char*)Ks + buf * 16384 + o);
      }
      {
        const int r = o >> 7, cb = o & 127;
        const int cs = cb ^ ((r & 7) << 4);
        gload16(VT + ((size_t)((b * 8 + h) * 128 + r)) * 1024 + kv0 + (cs >> 1),
                (char*)Vs + buf * 16384 + o);
      }
    }
  };

  stage(0, 0);
  asm volatile("s_waitcnt vmcnt(0)" ::: "memory");
  __syncthreads();

  int cur = 0;
  for (int t = 0; t < 16; ++t) {
    if (t < 15) stage(cur ^ 1, (t + 1) * 64);

    f32x4 sc[4];
    __builtin_amdgcn_s_setprio(1);
#pragma unroll
    for (int nb = 0; nb < 4; ++nb) {
      sc[nb] = fzero;
      const int rr = nb * 16 + ln;
      const int sw = (rr & 7) << 4;
#pragma unroll
      for (int kc = 0; kc < 4; ++kc) {
        const bf16x8 kf = *(const bf16x8*)((const char*)Ks + cur * 16384 + rr * 256 +
                                           (((kc * 32 + g * 8) << 1) ^ sw));
        sc[nb] = __builtin_amdgcn_mfma_f32_16x16x32_bf16(kf, qf[kc], sc[nb], 0, 0, 0);
      }
    }
    __builtin_amdgcn_s_setprio(0);

    float mnb[4];
#pragma unroll
    for (int nb = 0; nb < 4; ++nb)
      mnb[nb] = fmaxf(fmaxf(sc[nb][0], sc[nb][1]), fmaxf(sc[nb][2], sc[nb][3]));
    float pmax = fmaxf(fmaxf(mnb[0], mnb[1]), fmaxf(mnb[2], mnb[3]));
    pmax = fmaxf(pmax, __shfl_xor(pmax, 16));
    pmax = fmaxf(pmax, __shfl_xor(pmax, 32));
    if (__any(pmax > m_run + 11.5f)) {
      const float mnew = fmaxf(m_run, pmax);
      const float alpha = exp2v(m_run - mnew);
      l_run *= alpha;
      m_run = mnew;
      float ar[4];
#pragma unroll
      for (int r = 0; r < 4; ++r)
        ar[r] = __shfl(alpha, (lane & 48) | (((lane >> 4) & 3) << 2) | r);
#pragma unroll
      for (int i = 0; i < 8; i++)
#pragma unroll
        for (int r = 0; r < 4; r++) o_acc[i][r] *= ar[r];
    }
    float sum = 0.f;
    float pvv[16];
#pragma unroll
    for (int nb = 0; nb < 4; ++nb)
#pragma unroll
      for (int r = 0; r < 4; ++r) {
        const float p = exp2v(sc[nb][r] - m_run);
        pvv[nb * 4 + r] = p; sum += p;
      }
    l_run += sum;

    {
      char* pbase = (char*)Ps + w * 2048 + ln * 128;
#pragma unroll
      for (int nb = 0; nb < 4; ++nb) {
        uint2 pk;
        pk.x = cvtpk(pvv[nb * 4 + 0], pvv[nb * 4 + 1]);
        pk.y = cvtpk(pvv[nb * 4 + 2], pvv[nb * 4 + 3]);
        *(uint2*)(pbase + (((16 * nb + 4 * g) << 1) ^ ((ln & 7) << 4))) = pk;
      }
    }
    bf16x8 pf[2];
#pragma unroll
    for (int kc = 0; kc < 2; kc++)
      pf[kc] = *(const bf16x8*)((const char*)Ps + w * 2048 + ln * 128 +
                                (((kc * 32 + g * 8) << 1) ^ ((ln & 7) << 4)));

    __builtin_amdgcn_s_setprio(1);
#pragma unroll
    for (int nb2 = 0; nb2 < 8; ++nb2) {
      const int rr = nb2 * 16 + ln;
      const int sw = (rr & 7) << 4;
#pragma unroll
      for (int kc = 0; kc < 2; ++kc) {
        const bf16x8 vf = *(const bf16x8*)((const char*)Vs + cur * 16384 + rr * 128 +
                                           (((kc * 32 + g * 8) << 1) ^ sw));
        o_acc[nb2] = __builtin_amdgcn_mfma_f32_16x16x32_bf16(pf[kc], vf, o_acc[nb2], 0, 0, 0);
      }
    }
    __builtin_amdgcn_s_setprio(0);

    if (t < 15) {
      asm volatile("s_waitcnt vmcnt(0)" ::: "memory");
      __syncthreads();
    }
    cur ^= 1;
  }

  l_run += __shfl_xor(l_run, 16);
  l_run += __shfl_xor(l_run, 32);
  float rl[4];
#pragma unroll
  for (int r = 0; r < 4; ++r)
    rl[r] = 1.0f / __shfl(l_run, (lane & 48) | (((lane >> 4) & 3) << 2) | r);
  const int d_b = 32 * (cfg[b] + 1);
  const int zw = 128 - d_b;
  const size_t rowbase = (size_t)(b * 1024 + q0 + w * 16 + g * 4);
#pragma unroll
  for (int nb2 = 0; nb2 < 8; ++nb2) {
    const int dk = nb2 * 16 + ln;
    if (dk < d_b) {
#pragma unroll
      for (int r = 0; r < 4; r++)
        ret[(rowbase + r) * 1024 + h * d_b + dk] = f2bf(o_acc[nb2][r] * rl[r]);
    } else {
#pragma unroll
      for (int r = 0; r < 4; r++)
        ret[(rowbase + r) * 1024 + 8 * d_b + h * zw + (dk - d_b)] = 0;
    }
  }
}

// ---------------- launch ----------------
extern "C" void kernel_launch(void* const* d_in, const int* in_sizes, int n_in,
                              void* d_out, int out_size, void* d_ws, size_t ws_size,
                              hipStream_t stream)
{
  (void)in_sizes; (void)n_in; (void)out_size; (void)ws_size;
  const float* q   = (const float*)d_in[0];
  const float* k   = (const float*)d_in[1];
  const float* v   = (const float*)d_in[2];
  const int*   cfg = (const int*)d_in[3];
  const float* Wq  = (const float*)d_in[4];  const float* bq = (const float*)d_in[5];
  const float* Wk  = (const float*)d_in[6];  const float* bk = (const float*)d_in[7];
  const float* Wv  = (const float*)d_in[8];  const float* bv = (const float*)d_in[9];
  const float* Wo  = (const float*)d_in[10]; const float* bo = (const float*)d_in[11];

  const size_t X  = 8192ull * 1024ull;
  const size_t WN = 1024ull * 1024ull;
  char* p = (char*)d_ws;
  unsigned short* wb  = (unsigned short*)p; p += 4 * WN * 2;
  unsigned short* Qp  = (unsigned short*)p; p += X * 2;
  unsigned short* Kp  = (unsigned short*)p; p += X * 2;
  unsigned short* VTp = (unsigned short*)p; p += X * 2;
  unsigned short* ret = (unsigned short*)p; p += X * 2;

  convert_w<<<dim3(4096), dim3(256), 0, stream>>>(Wq, Wk, Wv, Wo, wb);

  gemmF<<<dim3(1536), dim3(512), 0, stream>>>(q, k, v, wb, bq, bk, bv,
                                              Qp, Kp, VTp);

  attn_kernel<<<dim3(512), dim3(512), 0, stream>>>(Qp, Kp, VTp, cfg, ret);

  gemm_out<<<dim3(256), dim3(512), 0, stream>>>(ret, wb + 3 * WN, bo, (float*)d_out);
}

// Round 14
// 170.559 us; speedup vs baseline: 1.0761x; 1.0761x over previous
//
#include <hip/hip_runtime.h>
#include <hip/hip_bf16.h>

// Fused MHA, B=8, S=1024, H=8, DK=128, D=1024, fp32 in/out, bf16 MFMA compute.
// convert -> QKV proj (256x128 3-buffer lead-2 counted-vmcnt GEMM, SINGLE-phase
// tile = 2 barriers/tile, 768 blocks = 3 exact rounds, XCD swizzle, V^T epilogue)
// -> flash attn (QBLK=128, swapped-QK in-lane softmax, cvt_pk, XCD swizzle,
// fused attn_arrange) -> out proj (same GEMM, 256 blocks = 1 round, fp32 out).
// [Round 14: revert to round-12 best (171.4 us) after gemmF fusion regression.]

typedef __attribute__((ext_vector_type(8))) __bf16 bf16x8;
typedef __attribute__((ext_vector_type(4))) float f32x4;

#define DEV static __device__ __forceinline__

DEV float exp2v(float x) { return __builtin_amdgcn_exp2f(x); }

DEV unsigned short f2bf(float f) {
  union { float f; unsigned int u; } c; c.f = f;
  unsigned int u = c.u + 0x7fffu + ((c.u >> 16) & 1u);
  return (unsigned short)(u >> 16);
}

DEV unsigned cvtpk(float a, float b) {
  unsigned r;
  asm("v_cvt_pk_bf16_f32 %0, %1, %2" : "=v"(r) : "v"(a), "v"(b));
  return r;
}

DEV void gload16(const void* g, void* l) {
  __builtin_amdgcn_global_load_lds((const __attribute__((address_space(1))) void*)g,
                                   (__attribute__((address_space(3))) void*)l, 16, 0, 0);
}

#define LGKM0 asm volatile("s_waitcnt lgkmcnt(0)" ::: "memory")
#define BAR   __builtin_amdgcn_s_barrier()
#define VMC6  asm volatile("s_waitcnt vmcnt(6)" ::: "memory")
#define VMC0  asm volatile("s_waitcnt vmcnt(0)" ::: "memory")

// ---------------- convert: fp32->bf16 ----------------
DEV void cv4(const float* __restrict__ s, unsigned short* __restrict__ d, int i) {
  const float4 a = *(const float4*)(s + i);
  ushort4 o;
  o.x = f2bf(a.x); o.y = f2bf(a.y); o.z = f2bf(a.z); o.w = f2bf(a.w);
  *(ushort4*)(d + i) = o;
}

__global__ __launch_bounds__(256) void convert_kernel(
    const float* __restrict__ q, const float* __restrict__ k, const float* __restrict__ v,
    const float* __restrict__ wq, const float* __restrict__ wk,
    const float* __restrict__ wv, const float* __restrict__ wo,
    unsigned short* __restrict__ xq, unsigned short* __restrict__ xk,
    unsigned short* __restrict__ xv, unsigned short* __restrict__ wb)
{
  const int i = (blockIdx.x * 256 + threadIdx.x) * 4;
  cv4(q, xq, i);
  cv4(k, xk, i);
  cv4(v, xv, i);
  if (i < 4 * 1024 * 1024) {
    const int which = i >> 20, off = i & 1048575;
    const float* s = which == 0 ? wq : which == 1 ? wk : which == 2 ? wv : wo;
    cv4(s, wb + (which << 20), off);
  }
}

// ---------------- 256x128 3-buffer lead-2 counted-vmcnt GEMM, 1 phase/tile ----------------
// C[m,n] = sum_k A[m,k]*Bt[n,k] + bias[n]. K=1024 = 16 BK=64 tiles.
// 512 thr = 8 waves (4M x 2N), per-wave 64x64 (acc[4][4]).
// LDS 144 KiB: A 3buf x 256x128B @0; B 3buf x 128x128B @98304. T2 XOR swizzle.
// Per tile t (ONE phase, 32 MFMA): {rdB + rdA(q0,q1) | stage A,B(t+2) | BAR
// lgkm0 | mm(0) mm(1) | gate VMC(6) | BAR}.
// Ledger: 6 loads/tile, lead 2 => gate leaves exactly t+2's 6 outstanding;
// buffer (t+2)%3's last readers finished at tile t-1's end-BAR.
// OUTMODE 0: QKV merged (z: 0=Q scaled, 1=K, 2=V^T packed), 768 blocks.
// OUTMODE 1: fp32 out (out projection), 256 blocks.
template<int OUTMODE>
__global__ __launch_bounds__(512, 1) void gemmS(
    const unsigned short* __restrict__ xq, const unsigned short* __restrict__ xk,
    const unsigned short* __restrict__ xv, const unsigned short* __restrict__ wb,
    const float* __restrict__ bq, const float* __restrict__ bk,
    const float* __restrict__ bv,
    unsigned short* __restrict__ Qp, unsigned short* __restrict__ Kp,
    unsigned short* __restrict__ VTp, float* __restrict__ fout)
{
  __shared__ __align__(16) char LDS[147456];
  int z, mt, nt;
  if (OUTMODE == 0) {        // 768 blocks = 8 XCD x 96
    const int swz = (blockIdx.x & 7) * 96 + (blockIdx.x >> 3);
    z = swz >> 8; const int rem = swz & 255; mt = rem >> 3; nt = rem & 7;
  } else {                   // 256 blocks = 8 XCD x 32
    const int swz = (blockIdx.x & 7) * 32 + (blockIdx.x >> 3);
    z = 0; mt = swz >> 3; nt = swz & 7;
  }
  const int m0 = mt * 256, n0 = nt * 128;
  const unsigned short* Ag = (OUTMODE == 1) ? xq : (z == 0 ? xq : z == 1 ? xk : xv);
  const unsigned short* Bg = (OUTMODE == 1) ? wb : wb + ((size_t)z << 20);
  const float* bias = (OUTMODE == 1) ? bq : (z == 0 ? bq : z == 1 ? bk : bv);

  const int tid = threadIdx.x, lane = tid & 63, w = tid >> 6;
  const int wm = w >> 1, wn = w & 1;      // 4M x 2N wave grid
  const int g = lane >> 4, ln = lane & 15;

  const f32x4 fzero = {0.f, 0.f, 0.f, 0.f};
  f32x4 acc[4][4];
#pragma unroll
  for (int i = 0; i < 4; i++)
#pragma unroll
    for (int j = 0; j < 4; j++) acc[i][j] = fzero;

  bf16x8 bfr[4][2];
  bf16x8 afr[4][2];   // all 4 A m-frags live for the single-phase tile

  auto SA = [&](int bf, int hf, int k0) {
    const unsigned short* src = Ag + (size_t)(m0 + hf * 128) * 1024 + k0;
    char* base = LDS + bf * 32768 + hf * 16384 + w * 2048;
#pragma unroll
    for (int r2 = 0; r2 < 2; ++r2) {
      const int o = w * 2048 + r2 * 1024 + lane * 16;
      const int rwi = o >> 7, cb = o & 127;
      gload16(src + (size_t)rwi * 1024 + ((cb ^ ((rwi & 7) << 4)) >> 1), base + r2 * 1024);
    }
  };
  auto SB = [&](int bf, int k0) {
    const unsigned short* src = Bg + (size_t)n0 * 1024 + k0;
    char* base = LDS + 98304 + bf * 16384 + w * 2048;
#pragma unroll
    for (int r2 = 0; r2 < 2; ++r2) {
      const int o = w * 2048 + r2 * 1024 + lane * 16;
      const int rwi = o >> 7, cb = o & 127;
      gload16(src + (size_t)rwi * 1024 + ((cb ^ ((rwi & 7) << 4)) >> 1), base + r2 * 1024);
    }
  };
  auto rdA = [&](int bf, int q) {
#pragma unroll
    for (int p = 0; p < 2; ++p) {
      const int row = wm * 64 + (2 * q + p) * 16 + ln;
      const int sw = (row & 7) << 4;
#pragma unroll
      for (int kc = 0; kc < 2; ++kc)
        afr[2 * q + p][kc] = *(const bf16x8*)(LDS + bf * 32768 + row * 128 + ((kc * 64 + g * 16) ^ sw));
    }
  };
  auto rdB = [&](int bf) {
#pragma unroll
    for (int nf = 0; nf < 4; ++nf) {
      const int row = wn * 64 + nf * 16 + ln;
      const int sw = (row & 7) << 4;
#pragma unroll
      for (int kc = 0; kc < 2; ++kc)
        bfr[nf][kc] = *(const bf16x8*)(LDS + 98304 + bf * 16384 + row * 128 + ((kc * 64 + g * 16) ^ sw));
    }
  };
  auto mm = [&](int q) {
    __builtin_amdgcn_s_setprio(1);
#pragma unroll
    for (int p = 0; p < 2; ++p)
#pragma unroll
      for (int nf = 0; nf < 4; ++nf)
#pragma unroll
        for (int kc = 0; kc < 2; ++kc)
          acc[2 * q + p][nf] =
              __builtin_amdgcn_mfma_f32_16x16x32_bf16(afr[2 * q + p][kc], bfr[nf][kc],
                                                      acc[2 * q + p][nf], 0, 0, 0);
    __builtin_amdgcn_s_setprio(0);
  };

  // prologue: tiles 0,1 fully staged (12 loads); gate leaves tile1's 6 in flight
  SA(0, 0, 0); SA(0, 1, 0); SB(0, 0);
  SA(1, 0, 64); SA(1, 1, 64); SB(1, 64);
  VMC6; BAR;

  int br = 0, bw = 2;
  for (int t = 0; t < 16; ++t) {
    const int kL = (t + 2) << 6;
    // single phase: all reads of tile t, all stages of tile t+2
    rdB(br); rdA(br, 0); rdA(br, 1);
    if (t < 14) { SA(bw, 0, kL); SA(bw, 1, kL); SB(bw, kL); }
    BAR; LGKM0;
    mm(0); mm(1);
    if (t < 14) { VMC6; } else if (t == 14) { VMC0; }
    BAR;
    br = br == 2 ? 0 : br + 1;
    bw = bw == 2 ? 0 : bw + 1;
  }

  // epilogue
  const float QS = 0.12751743f;   // 1/sqrt(128)*log2(e)
#pragma unroll
  for (int mf = 0; mf < 4; ++mf)
#pragma unroll
    for (int nf = 0; nf < 4; ++nf) {
      const int m = m0 + wm * 64 + mf * 16 + g * 4;
      const int n = n0 + wn * 64 + nf * 16 + ln;
      const float bn = bias[n];
      if (OUTMODE == 1) {
#pragma unroll
        for (int r = 0; r < 4; ++r)
          fout[(size_t)(m + r) * 1024 + n] = acc[mf][nf][r] + bn;
      } else if (z == 0) {
#pragma unroll
        for (int r = 0; r < 4; ++r)
          Qp[(size_t)(m + r) * 1024 + n] = f2bf((acc[mf][nf][r] + bn) * QS);
      } else if (z == 1) {
#pragma unroll
        for (int r = 0; r < 4; ++r)
          Kp[(size_t)(m + r) * 1024 + n] = f2bf(acc[mf][nf][r] + bn);
      } else {
        const int b = m >> 10, s0 = m & 1023;   // n = h*128+dk
        uint2 pk;
        pk.x = cvtpk(acc[mf][nf][0] + bn, acc[mf][nf][1] + bn);
        pk.y = cvtpk(acc[mf][nf][2] + bn, acc[mf][nf][3] + bn);
        *(uint2*)(VTp + (((size_t)(b * 1024 + n)) << 10) + s0) = pk;
      }
    }
}

// ---------------- flash attention + fused attn_arrange (+zero pad) ----------------
// Grid 512 = 8 qb x 64 (b,h); XCD-coherent. 512 thr = 8 waves x 16 q-rows (QBLK 128).
__global__ __launch_bounds__(512) void attn_kernel(
    const unsigned short* __restrict__ Qp, const unsigned short* __restrict__ Kp,
    const unsigned short* __restrict__ VT, const int* __restrict__ cfg,
    unsigned short* __restrict__ ret)
{
  __shared__ __align__(16) unsigned short Ks[2][64 * 128];
  __shared__ __align__(16) unsigned short Vs[2][128 * 64];
  __shared__ __align__(16) unsigned short Ps[8 * 16 * 64];
  const int bx = blockIdx.x;
  const int qb = bx >> 6, bh = bx & 63, b = bh >> 3, h = bh & 7;
  const int tid = threadIdx.x, lane = tid & 63, w = tid >> 6;
  const int g = lane >> 4, ln = lane & 15;
  const int q0 = qb * 128;
  const f32x4 fzero = {0.f, 0.f, 0.f, 0.f};

  bf16x8 qf[4];
  {
    const unsigned short* qrow = Qp + ((size_t)(b * 1024 + q0 + w * 16 + ln)) * 1024 + h * 128;
#pragma unroll
    for (int kc = 0; kc < 4; kc++) qf[kc] = *(const bf16x8*)(qrow + kc * 32 + g * 8);
  }
  float m_run = -1e30f, l_run = 0.f;
  f32x4 o_acc[8];
#pragma unroll
  for (int i = 0; i < 8; i++) o_acc[i] = fzero;

  auto stage = [&](int buf, int kv0) {
#pragma unroll
    for (int i = 0; i < 2; ++i) {
      const int o = i * 8192 + tid * 16;
      {
        const int r = o >> 8, cb = o & 255;
        const int cs = cb ^ ((r & 7) << 4);
        gload16(Kp + ((size_t)(b * 1024 + kv0 + r)) * 1024 + h * 128 + (cs >> 1),
                (char*)Ks + buf * 16384 + o);
      }
      {
        const int r = o >> 7, cb = o & 127;
        const int cs = cb ^ ((r & 7) << 4);
        gload16(VT + ((size_t)((b * 8 + h) * 128 + r)) * 1024 + kv0 + (cs >> 1),
                (char*)Vs + buf * 16384 + o);
      }
    }
  };

  stage(0, 0);
  asm volatile("s_waitcnt vmcnt(0)" ::: "memory");
  __syncthreads();

  int cur = 0;
  for (int t = 0; t < 16; ++t) {
    if (t < 15) stage(cur ^ 1, (t + 1) * 64);

    f32x4 sc[4];
    __builtin_amdgcn_s_setprio(1);
#pragma unroll
    for (int nb = 0; nb < 4; ++nb) {
      sc[nb] = fzero;
      const int rr = nb * 16 + ln;
      const int sw = (rr & 7) << 4;
#pragma unroll
      for (int kc = 0; kc < 4; ++kc) {
        const bf16x8 kf = *(const bf16x8*)((const char*)Ks + cur * 16384 + rr * 256 +
                                           (((kc * 32 + g * 8) << 1) ^ sw));
        sc[nb] = __builtin_amdgcn_mfma_f32_16x16x32_bf16(kf, qf[kc], sc[nb], 0, 0, 0);
      }
    }
    __builtin_amdgcn_s_setprio(0);

    float mnb[4];
#pragma unroll
    for (int nb = 0; nb < 4; ++nb)
      mnb[nb] = fmaxf(fmaxf(sc[nb][0], sc[nb][1]), fmaxf(sc[nb][2], sc[nb][3]));
    float pmax = fmaxf(fmaxf(mnb[0], mnb[1]), fmaxf(mnb[2], mnb[3]));
    pmax = fmaxf(pmax, __shfl_xor(pmax, 16));
    pmax = fmaxf(pmax, __shfl_xor(pmax, 32));
    if (__any(pmax > m_run + 11.5f)) {
      const float mnew = fmaxf(m_run, pmax);
      const float alpha = exp2v(m_run - mnew);
      l_run *= alpha;
      m_run = mnew;
      float ar[4];
#pragma unroll
      for (int r = 0; r < 4; ++r)
        ar[r] = __shfl(alpha, (lane & 48) | (((lane >> 4) & 3) << 2) | r);
#pragma unroll
      for (int i = 0; i < 8; i++)
#pragma unroll
        for (int r = 0; r < 4; r++) o_acc[i][r] *= ar[r];
    }
    float sum = 0.f;
    float pvv[16];
#pragma unroll
    for (int nb = 0; nb < 4; ++nb)
#pragma unroll
      for (int r = 0; r < 4; ++r) {
        const float p = exp2v(sc[nb][r] - m_run);
        pvv[nb * 4 + r] = p; sum += p;
      }
    l_run += sum;

    {
      char* pbase = (char*)Ps + w * 2048 + ln * 128;
#pragma unroll
      for (int nb = 0; nb < 4; ++nb) {
        uint2 pk;
        pk.x = cvtpk(pvv[nb * 4 + 0], pvv[nb * 4 + 1]);
        pk.y = cvtpk(pvv[nb * 4 + 2], pvv[nb * 4 + 3]);
        *(uint2*)(pbase + (((16 * nb + 4 * g) << 1) ^ ((ln & 7) << 4))) = pk;
      }
    }
    bf16x8 pf[2];
#pragma unroll
    for (int kc = 0; kc < 2; kc++)
      pf[kc] = *(const bf16x8*)((const char*)Ps + w * 2048 + ln * 128 +
                                (((kc * 32 + g * 8) << 1) ^ ((ln & 7) << 4)));

    __builtin_amdgcn_s_setprio(1);
#pragma unroll
    for (int nb2 = 0; nb2 < 8; ++nb2) {
      const int rr = nb2 * 16 + ln;
      const int sw = (rr & 7) << 4;
#pragma unroll
      for (int kc = 0; kc < 2; ++kc) {
        const bf16x8 vf = *(const bf16x8*)((const char*)Vs + cur * 16384 + rr * 128 +
                                           (((kc * 32 + g * 8) << 1) ^ sw));
        o_acc[nb2] = __builtin_amdgcn_mfma_f32_16x16x32_bf16(pf[kc], vf, o_acc[nb2], 0, 0, 0);
      }
    }
    __builtin_amdgcn_s_setprio(0);

    if (t < 15) {
      asm volatile("s_waitcnt vmcnt(0)" ::: "memory");
      __syncthreads();
    }
    cur ^= 1;
  }

  l_run += __shfl_xor(l_run, 16);
  l_run += __shfl_xor(l_run, 32);
  float rl[4];
#pragma unroll
  for (int r = 0; r < 4; ++r)
    rl[r] = 1.0f / __shfl(l_run, (lane & 48) | (((lane >> 4) & 3) << 2) | r);
  const int d_b = 32 * (cfg[b] + 1);
  const int zw = 128 - d_b;
  const size_t rowbase = (size_t)(b * 1024 + q0 + w * 16 + g * 4);
#pragma unroll
  for (int nb2 = 0; nb2 < 8; ++nb2) {
    const int dk = nb2 * 16 + ln;
    if (dk < d_b) {
#pragma unroll
      for (int r = 0; r < 4; r++)
        ret[(rowbase + r) * 1024 + h * d_b + dk] = f2bf(o_acc[nb2][r] * rl[r]);
    } else {
#pragma unroll
      for (int r = 0; r < 4; r++)
        ret[(rowbase + r) * 1024 + 8 * d_b + h * zw + (dk - d_b)] = 0;
    }
  }
}

// ---------------- launch ----------------
extern "C" void kernel_launch(void* const* d_in, const int* in_sizes, int n_in,
                              void* d_out, int out_size, void* d_ws, size_t ws_size,
                              hipStream_t stream)
{
  (void)in_sizes; (void)n_in; (void)out_size; (void)ws_size;
  const float* q   = (const float*)d_in[0];
  const float* k   = (const float*)d_in[1];
  const float* v   = (const float*)d_in[2];
  const int*   cfg = (const int*)d_in[3];
  const float* Wq  = (const float*)d_in[4];  const float* bq = (const float*)d_in[5];
  const float* Wk  = (const float*)d_in[6];  const float* bk = (const float*)d_in[7];
  const float* Wv  = (const float*)d_in[8];  const float* bv = (const float*)d_in[9];
  const float* Wo  = (const float*)d_in[10]; const float* bo = (const float*)d_in[11];

  const size_t X  = 8192ull * 1024ull;
  const size_t WN = 1024ull * 1024ull;
  char* p = (char*)d_ws;
  unsigned short* xq  = (unsigned short*)p; p += X * 2;
  unsigned short* xk  = (unsigned short*)p; p += X * 2;
  unsigned short* xv  = (unsigned short*)p; p += X * 2;
  unsigned short* wb  = (unsigned short*)p; p += 4 * WN * 2;
  unsigned short* Qp  = (unsigned short*)p; p += X * 2;
  unsigned short* Kp  = (unsigned short*)p; p += X * 2;
  unsigned short* VTp = (unsigned short*)p; p += X * 2;
  unsigned short* ret = (unsigned short*)p; p += X * 2;

  convert_kernel<<<dim3(8192), dim3(256), 0, stream>>>(q, k, v, Wq, Wk, Wv, Wo,
                                                       xq, xk, xv, wb);

  gemmS<0><<<dim3(768), dim3(512), 0, stream>>>(xq, xk, xv, wb, bq, bk, bv,
                                                Qp, Kp, VTp, nullptr);

  attn_kernel<<<dim3(512), dim3(512), 0, stream>>>(Qp, Kp, VTp, cfg, ret);

  gemmS<1><<<dim3(256), dim3(512), 0, stream>>>(ret, nullptr, nullptr, wb + 3 * WN,
                                                bo, nullptr, nullptr,
                                                nullptr, nullptr, nullptr,
                                                (float*)d_out);
}